// Round 1
// baseline (2430.030 us; speedup 1.0000x reference)
//
#include <hip/hip_runtime.h>
#include <math.h>

#define RK   16
#define H0   512
#define W0   1024
#define H1   2048
#define W1   4096
#define HW0  (H0*W0)
#define HW1  (H1*W1)
#define NH   128
#define BLK  256

__device__ __forceinline__ float softplusf(float x) {
    // matches jax.nn.softplus = logaddexp(x, 0)
    return fmaxf(x, 0.f) + log1pf(expf(-fabsf(x)));
}

__global__ __launch_bounds__(BLK) void bg_fused_kernel(
    const float* __restrict__ vd,
    const float* __restrict__ m0,
    const float* __restrict__ m1,
    const float* __restrict__ w1,
    const float* __restrict__ w2,
    float* __restrict__ out,
    int B)
{
    __shared__ float w1T[NH * 16];  // [j][r]  (transposed: r contiguous -> ds_read_b128)
    __shared__ float w2s[NH * 4];   // [j][c]  padded stride 4

    const int t = threadIdx.x;
    for (int i = t; i < NH * 16; i += BLK) {
        int j = i >> 4, r = i & 15;
        w1T[i] = w1[r * NH + j];
    }
    for (int i = t; i < NH * 4; i += BLK) {
        int j = i >> 2, c = i & 3;
        w2s[i] = (c < 3) ? w2[j * 3 + c] : 0.f;
    }
    __syncthreads();

    const int b = blockIdx.x * BLK + t;
    if (b >= B) return;

    // ---- unwrap_equirect ----
    float x = vd[b * 3 + 0], y = vd[b * 3 + 1], z = vd[b * 3 + 2];
    float inv = 1.f / (sqrtf(fmaf(x, x, fmaf(y, y, z * z))) + 1e-8f);
    float dx = x * inv, dy = y * inv, dz = z * inv;
    const float INVPI = 0.31830988618379067154f;
    float gx = atan2f(dx, dy) * INVPI;
    float cz = fminf(fmaxf(dz, -1.f), 1.f);
    float gy = acosf(cz) * (2.f * INVPI) - 1.f;

    // ---- bilinear setup: 4 (offset, weight) pairs per mat; invalid corners -> w=0 ----
    int   off[8];
    float wt[8];
    {
        float px = (gx + 1.f) * (0.5f * W0) - 0.5f;
        float py = (gy + 1.f) * (0.5f * H0) - 0.5f;
        float fx0 = floorf(px), fy0 = floorf(py);
        int x0 = (int)fx0, y0 = (int)fy0, x1 = x0 + 1, y1 = y0 + 1;
        float wx1 = px - fx0, wy1 = py - fy0;
        float wx0 = 1.f - wx1, wy0 = 1.f - wy1;
        bool vx0 = (x0 >= 0) & (x0 < W0), vx1 = (x1 >= 0) & (x1 < W0);
        bool vy0 = (y0 >= 0) & (y0 < H0), vy1 = (y1 >= 0) & (y1 < H0);
        int xc0 = min(max(x0, 0), W0 - 1), xc1 = min(max(x1, 0), W0 - 1);
        int yc0 = min(max(y0, 0), H0 - 1), yc1 = min(max(y1, 0), H0 - 1);
        off[0] = yc0 * W0 + xc0; wt[0] = (vx0 && vy0) ? wx0 * wy0 : 0.f;
        off[1] = yc0 * W0 + xc1; wt[1] = (vx1 && vy0) ? wx1 * wy0 : 0.f;
        off[2] = yc1 * W0 + xc0; wt[2] = (vx0 && vy1) ? wx0 * wy1 : 0.f;
        off[3] = yc1 * W0 + xc1; wt[3] = (vx1 && vy1) ? wx1 * wy1 : 0.f;
    }
    {
        float px = (gx + 1.f) * (0.5f * W1) - 0.5f;
        float py = (gy + 1.f) * (0.5f * H1) - 0.5f;
        float fx0 = floorf(px), fy0 = floorf(py);
        int x0 = (int)fx0, y0 = (int)fy0, x1 = x0 + 1, y1 = y0 + 1;
        float wx1 = px - fx0, wy1 = py - fy0;
        float wx0 = 1.f - wx1, wy0 = 1.f - wy1;
        bool vx0 = (x0 >= 0) & (x0 < W1), vx1 = (x1 >= 0) & (x1 < W1);
        bool vy0 = (y0 >= 0) & (y0 < H1), vy1 = (y1 >= 0) & (y1 < H1);
        int xc0 = min(max(x0, 0), W1 - 1), xc1 = min(max(x1, 0), W1 - 1);
        int yc0 = min(max(y0, 0), H1 - 1), yc1 = min(max(y1, 0), H1 - 1);
        // 0.5 scale for the fine map folded into the weights
        off[4] = yc0 * W1 + xc0; wt[4] = (vx0 && vy0) ? 0.5f * wx0 * wy0 : 0.f;
        off[5] = yc0 * W1 + xc1; wt[5] = (vx1 && vy0) ? 0.5f * wx1 * wy0 : 0.f;
        off[6] = yc1 * W1 + xc0; wt[6] = (vx0 && vy1) ? 0.5f * wx0 * wy1 : 0.f;
        off[7] = yc1 * W1 + xc1; wt[7] = (vx1 && vy1) ? 0.5f * wx1 * wy1 : 0.f;
    }

    // ---- gather 16 channels from both maps ----
    float emb[RK];
    #pragma unroll
    for (int r = 0; r < RK; ++r) {
        const float* p0 = m0 + r * HW0;
        const float* p1 = m1 + r * HW1;
        float v = p0[off[0]] * wt[0];
        v = fmaf(p0[off[1]], wt[1], v);
        v = fmaf(p0[off[2]], wt[2], v);
        v = fmaf(p0[off[3]], wt[3], v);
        v = fmaf(p1[off[4]], wt[4], v);
        v = fmaf(p1[off[5]], wt[5], v);
        v = fmaf(p1[off[6]], wt[6], v);
        v = fmaf(p1[off[7]], wt[7], v);
        emb[r] = v;
    }

    // ---- MLP: relu(emb @ w1) @ w2, softplus ----
    float a0 = 0.f, a1 = 0.f, a2 = 0.f;
    #pragma unroll 8
    for (int j = 0; j < NH; ++j) {
        const float4* wp = (const float4*)&w1T[j * 16];
        float4 c0 = wp[0], c1 = wp[1], c2 = wp[2], c3 = wp[3];
        float h;
        h = emb[0] * c0.x;
        h = fmaf(emb[1],  c0.y, h);
        h = fmaf(emb[2],  c0.z, h);
        h = fmaf(emb[3],  c0.w, h);
        h = fmaf(emb[4],  c1.x, h);
        h = fmaf(emb[5],  c1.y, h);
        h = fmaf(emb[6],  c1.z, h);
        h = fmaf(emb[7],  c1.w, h);
        h = fmaf(emb[8],  c2.x, h);
        h = fmaf(emb[9],  c2.y, h);
        h = fmaf(emb[10], c2.z, h);
        h = fmaf(emb[11], c2.w, h);
        h = fmaf(emb[12], c3.x, h);
        h = fmaf(emb[13], c3.y, h);
        h = fmaf(emb[14], c3.z, h);
        h = fmaf(emb[15], c3.w, h);
        h = fmaxf(h, 0.f);
        a0 = fmaf(h, w2s[j * 4 + 0], a0);
        a1 = fmaf(h, w2s[j * 4 + 1], a1);
        a2 = fmaf(h, w2s[j * 4 + 2], a2);
    }

    out[b * 3 + 0] = softplusf(a0);
    out[b * 3 + 1] = softplusf(a1);
    out[b * 3 + 2] = softplusf(a2);
}

extern "C" void kernel_launch(void* const* d_in, const int* in_sizes, int n_in,
                              void* d_out, int out_size, void* d_ws, size_t ws_size,
                              hipStream_t stream) {
    const float* vd = (const float*)d_in[0];
    const float* m0 = (const float*)d_in[1];
    const float* m1 = (const float*)d_in[2];
    const float* w1 = (const float*)d_in[3];
    const float* w2 = (const float*)d_in[4];
    float* out = (float*)d_out;
    int B = in_sizes[0] / 3;
    int grid = (B + BLK - 1) / BLK;
    bg_fused_kernel<<<grid, BLK, 0, stream>>>(vd, m0, m1, w1, w2, out, B);
}

// Round 2
// 863.771 us; speedup vs baseline: 2.8133x; 2.8133x over previous
//
#include <hip/hip_runtime.h>
#include <math.h>

#define RK   16
#define H0   512
#define W0   1024
#define H1   2048
#define W1   4096
#define HW0  (H0*W0)
#define HW1  (H1*W1)
#define NH   128
#define BLK  256

__device__ __forceinline__ float softplusf(float x) {
    return fmaxf(x, 0.f) + log1pf(expf(-fabsf(x)));
}

__device__ __forceinline__ unsigned bf16rne(float f) {
    unsigned x = __float_as_uint(f);
    return (x + 0x7fffu + ((x >> 16) & 1u)) >> 16;
}

// ---- repack (16, H, W) fp32 -> (H, W, 16) bf16 (packed as 8 uint32/pixel) ----
__global__ __launch_bounds__(BLK) void repack_kernel(
    const float* __restrict__ src, unsigned* __restrict__ dst, int HW)
{
    int p = blockIdx.x * BLK + threadIdx.x;
    if (p >= HW) return;
    unsigned u[8];
    #pragma unroll
    for (int r = 0; r < 8; ++r) {
        float a = src[(2 * r) * HW + p];      // channel 2r   -> low 16
        float b = src[(2 * r + 1) * HW + p];  // channel 2r+1 -> high 16
        u[r] = bf16rne(a) | (bf16rne(b) << 16);
    }
    uint4* q = (uint4*)(dst + (size_t)p * 8);
    q[0] = make_uint4(u[0], u[1], u[2], u[3]);
    q[1] = make_uint4(u[4], u[5], u[6], u[7]);
}

__device__ __forceinline__ void accum_corner(
    const unsigned* __restrict__ mat, int off, float wt, float* emb)
{
    const uint4* q = (const uint4*)(mat + (size_t)off * 8);
    uint4 u0 = q[0];
    uint4 u1 = q[1];
    unsigned w[8] = {u0.x, u0.y, u0.z, u0.w, u1.x, u1.y, u1.z, u1.w};
    #pragma unroll
    for (int r = 0; r < 8; ++r) {
        float lo = __uint_as_float(w[r] << 16);
        float hi = __uint_as_float(w[r] & 0xffff0000u);
        emb[2 * r]     = fmaf(lo, wt, emb[2 * r]);
        emb[2 * r + 1] = fmaf(hi, wt, emb[2 * r + 1]);
    }
}

// ---- fused gather + MLP, reading repacked bf16 pixel-major maps ----
__global__ __launch_bounds__(BLK) void bg_gather_kernel(
    const float* __restrict__ vd,
    const unsigned* __restrict__ m0p,
    const unsigned* __restrict__ m1p,
    const float* __restrict__ w1,
    const float* __restrict__ w2,
    float* __restrict__ out,
    int B)
{
    __shared__ float w1T[NH * 16];  // [j][r]
    __shared__ float w2s[NH * 4];   // [j][c] padded

    const int t = threadIdx.x;
    for (int i = t; i < NH * 16; i += BLK) {
        int j = i >> 4, r = i & 15;
        w1T[i] = w1[r * NH + j];
    }
    for (int i = t; i < NH * 4; i += BLK) {
        int j = i >> 2, c = i & 3;
        w2s[i] = (c < 3) ? w2[j * 3 + c] : 0.f;
    }
    __syncthreads();

    const int b = blockIdx.x * BLK + t;
    if (b >= B) return;

    float x = vd[b * 3 + 0], y = vd[b * 3 + 1], z = vd[b * 3 + 2];
    float inv = 1.f / (sqrtf(fmaf(x, x, fmaf(y, y, z * z))) + 1e-8f);
    float dx = x * inv, dy = y * inv, dz = z * inv;
    const float INVPI = 0.31830988618379067154f;
    float gx = atan2f(dx, dy) * INVPI;
    float cz = fminf(fmaxf(dz, -1.f), 1.f);
    float gy = acosf(cz) * (2.f * INVPI) - 1.f;

    int   off[8];
    float wt[8];
    {
        float px = (gx + 1.f) * (0.5f * W0) - 0.5f;
        float py = (gy + 1.f) * (0.5f * H0) - 0.5f;
        float fx0 = floorf(px), fy0 = floorf(py);
        int x0 = (int)fx0, y0 = (int)fy0, x1 = x0 + 1, y1 = y0 + 1;
        float wx1 = px - fx0, wy1 = py - fy0;
        float wx0 = 1.f - wx1, wy0 = 1.f - wy1;
        bool vx0 = (x0 >= 0) & (x0 < W0), vx1 = (x1 >= 0) & (x1 < W0);
        bool vy0 = (y0 >= 0) & (y0 < H0), vy1 = (y1 >= 0) & (y1 < H0);
        int xc0 = min(max(x0, 0), W0 - 1), xc1 = min(max(x1, 0), W0 - 1);
        int yc0 = min(max(y0, 0), H0 - 1), yc1 = min(max(y1, 0), H0 - 1);
        off[0] = yc0 * W0 + xc0; wt[0] = (vx0 && vy0) ? wx0 * wy0 : 0.f;
        off[1] = yc0 * W0 + xc1; wt[1] = (vx1 && vy0) ? wx1 * wy0 : 0.f;
        off[2] = yc1 * W0 + xc0; wt[2] = (vx0 && vy1) ? wx0 * wy1 : 0.f;
        off[3] = yc1 * W0 + xc1; wt[3] = (vx1 && vy1) ? wx1 * wy1 : 0.f;
    }
    {
        float px = (gx + 1.f) * (0.5f * W1) - 0.5f;
        float py = (gy + 1.f) * (0.5f * H1) - 0.5f;
        float fx0 = floorf(px), fy0 = floorf(py);
        int x0 = (int)fx0, y0 = (int)fy0, x1 = x0 + 1, y1 = y0 + 1;
        float wx1 = px - fx0, wy1 = py - fy0;
        float wx0 = 1.f - wx1, wy0 = 1.f - wy1;
        bool vx0 = (x0 >= 0) & (x0 < W1), vx1 = (x1 >= 0) & (x1 < W1);
        bool vy0 = (y0 >= 0) & (y0 < H1), vy1 = (y1 >= 0) & (y1 < H1);
        int xc0 = min(max(x0, 0), W1 - 1), xc1 = min(max(x1, 0), W1 - 1);
        int yc0 = min(max(y0, 0), H1 - 1), yc1 = min(max(y1, 0), H1 - 1);
        off[4] = yc0 * W1 + xc0; wt[4] = (vx0 && vy0) ? 0.5f * wx0 * wy0 : 0.f;
        off[5] = yc0 * W1 + xc1; wt[5] = (vx1 && vy0) ? 0.5f * wx1 * wy0 : 0.f;
        off[6] = yc1 * W1 + xc0; wt[6] = (vx0 && vy1) ? 0.5f * wx0 * wy1 : 0.f;
        off[7] = yc1 * W1 + xc1; wt[7] = (vx1 && vy1) ? 0.5f * wx1 * wy1 : 0.f;
    }

    float emb[RK];
    #pragma unroll
    for (int r = 0; r < RK; ++r) emb[r] = 0.f;
    accum_corner(m0p, off[0], wt[0], emb);
    accum_corner(m0p, off[1], wt[1], emb);
    accum_corner(m0p, off[2], wt[2], emb);
    accum_corner(m0p, off[3], wt[3], emb);
    accum_corner(m1p, off[4], wt[4], emb);
    accum_corner(m1p, off[5], wt[5], emb);
    accum_corner(m1p, off[6], wt[6], emb);
    accum_corner(m1p, off[7], wt[7], emb);

    float a0 = 0.f, a1 = 0.f, a2 = 0.f;
    #pragma unroll 8
    for (int j = 0; j < NH; ++j) {
        const float4* wp = (const float4*)&w1T[j * 16];
        float4 c0 = wp[0], c1 = wp[1], c2 = wp[2], c3 = wp[3];
        float h;
        h = emb[0] * c0.x;
        h = fmaf(emb[1],  c0.y, h);
        h = fmaf(emb[2],  c0.z, h);
        h = fmaf(emb[3],  c0.w, h);
        h = fmaf(emb[4],  c1.x, h);
        h = fmaf(emb[5],  c1.y, h);
        h = fmaf(emb[6],  c1.z, h);
        h = fmaf(emb[7],  c1.w, h);
        h = fmaf(emb[8],  c2.x, h);
        h = fmaf(emb[9],  c2.y, h);
        h = fmaf(emb[10], c2.z, h);
        h = fmaf(emb[11], c2.w, h);
        h = fmaf(emb[12], c3.x, h);
        h = fmaf(emb[13], c3.y, h);
        h = fmaf(emb[14], c3.z, h);
        h = fmaf(emb[15], c3.w, h);
        h = fmaxf(h, 0.f);
        a0 = fmaf(h, w2s[j * 4 + 0], a0);
        a1 = fmaf(h, w2s[j * 4 + 1], a1);
        a2 = fmaf(h, w2s[j * 4 + 2], a2);
    }

    out[b * 3 + 0] = softplusf(a0);
    out[b * 3 + 1] = softplusf(a1);
    out[b * 3 + 2] = softplusf(a2);
}

// ---- fallback: direct fp32 gather from channel-major maps (R1 kernel) ----
__global__ __launch_bounds__(BLK) void bg_fused_kernel(
    const float* __restrict__ vd,
    const float* __restrict__ m0,
    const float* __restrict__ m1,
    const float* __restrict__ w1,
    const float* __restrict__ w2,
    float* __restrict__ out,
    int B)
{
    __shared__ float w1T[NH * 16];
    __shared__ float w2s[NH * 4];

    const int t = threadIdx.x;
    for (int i = t; i < NH * 16; i += BLK) {
        int j = i >> 4, r = i & 15;
        w1T[i] = w1[r * NH + j];
    }
    for (int i = t; i < NH * 4; i += BLK) {
        int j = i >> 2, c = i & 3;
        w2s[i] = (c < 3) ? w2[j * 3 + c] : 0.f;
    }
    __syncthreads();

    const int b = blockIdx.x * BLK + t;
    if (b >= B) return;

    float x = vd[b * 3 + 0], y = vd[b * 3 + 1], z = vd[b * 3 + 2];
    float inv = 1.f / (sqrtf(fmaf(x, x, fmaf(y, y, z * z))) + 1e-8f);
    float dx = x * inv, dy = y * inv, dz = z * inv;
    const float INVPI = 0.31830988618379067154f;
    float gx = atan2f(dx, dy) * INVPI;
    float cz = fminf(fmaxf(dz, -1.f), 1.f);
    float gy = acosf(cz) * (2.f * INVPI) - 1.f;

    int   off[8];
    float wt[8];
    {
        float px = (gx + 1.f) * (0.5f * W0) - 0.5f;
        float py = (gy + 1.f) * (0.5f * H0) - 0.5f;
        float fx0 = floorf(px), fy0 = floorf(py);
        int x0 = (int)fx0, y0 = (int)fy0, x1 = x0 + 1, y1 = y0 + 1;
        float wx1 = px - fx0, wy1 = py - fy0;
        float wx0 = 1.f - wx1, wy0 = 1.f - wy1;
        bool vx0 = (x0 >= 0) & (x0 < W0), vx1 = (x1 >= 0) & (x1 < W0);
        bool vy0 = (y0 >= 0) & (y0 < H0), vy1 = (y1 >= 0) & (y1 < H0);
        int xc0 = min(max(x0, 0), W0 - 1), xc1 = min(max(x1, 0), W0 - 1);
        int yc0 = min(max(y0, 0), H0 - 1), yc1 = min(max(y1, 0), H0 - 1);
        off[0] = yc0 * W0 + xc0; wt[0] = (vx0 && vy0) ? wx0 * wy0 : 0.f;
        off[1] = yc0 * W0 + xc1; wt[1] = (vx1 && vy0) ? wx1 * wy0 : 0.f;
        off[2] = yc1 * W0 + xc0; wt[2] = (vx0 && vy1) ? wx0 * wy1 : 0.f;
        off[3] = yc1 * W0 + xc1; wt[3] = (vx1 && vy1) ? wx1 * wy1 : 0.f;
    }
    {
        float px = (gx + 1.f) * (0.5f * W1) - 0.5f;
        float py = (gy + 1.f) * (0.5f * H1) - 0.5f;
        float fx0 = floorf(px), fy0 = floorf(py);
        int x0 = (int)fx0, y0 = (int)fy0, x1 = x0 + 1, y1 = y0 + 1;
        float wx1 = px - fx0, wy1 = py - fy0;
        float wx0 = 1.f - wx1, wy0 = 1.f - wy1;
        bool vx0 = (x0 >= 0) & (x0 < W1), vx1 = (x1 >= 0) & (x1 < W1);
        bool vy0 = (y0 >= 0) & (y0 < H1), vy1 = (y1 >= 0) & (y1 < H1);
        int xc0 = min(max(x0, 0), W1 - 1), xc1 = min(max(x1, 0), W1 - 1);
        int yc0 = min(max(y0, 0), H1 - 1), yc1 = min(max(y1, 0), H1 - 1);
        off[4] = yc0 * W1 + xc0; wt[4] = (vx0 && vy0) ? 0.5f * wx0 * wy0 : 0.f;
        off[5] = yc0 * W1 + xc1; wt[5] = (vx1 && vy0) ? 0.5f * wx1 * wy0 : 0.f;
        off[6] = yc1 * W1 + xc0; wt[6] = (vx0 && vy1) ? 0.5f * wx0 * wy1 : 0.f;
        off[7] = yc1 * W1 + xc1; wt[7] = (vx1 && vy1) ? 0.5f * wx1 * wy1 : 0.f;
    }

    float emb[RK];
    #pragma unroll
    for (int r = 0; r < RK; ++r) {
        const float* p0 = m0 + r * HW0;
        const float* p1 = m1 + (size_t)r * HW1;
        float v = p0[off[0]] * wt[0];
        v = fmaf(p0[off[1]], wt[1], v);
        v = fmaf(p0[off[2]], wt[2], v);
        v = fmaf(p0[off[3]], wt[3], v);
        v = fmaf(p1[off[4]], wt[4], v);
        v = fmaf(p1[off[5]], wt[5], v);
        v = fmaf(p1[off[6]], wt[6], v);
        v = fmaf(p1[off[7]], wt[7], v);
        emb[r] = v;
    }

    float a0 = 0.f, a1 = 0.f, a2 = 0.f;
    #pragma unroll 8
    for (int j = 0; j < NH; ++j) {
        const float4* wp = (const float4*)&w1T[j * 16];
        float4 c0 = wp[0], c1 = wp[1], c2 = wp[2], c3 = wp[3];
        float h;
        h = emb[0] * c0.x;
        h = fmaf(emb[1],  c0.y, h);
        h = fmaf(emb[2],  c0.z, h);
        h = fmaf(emb[3],  c0.w, h);
        h = fmaf(emb[4],  c1.x, h);
        h = fmaf(emb[5],  c1.y, h);
        h = fmaf(emb[6],  c1.z, h);
        h = fmaf(emb[7],  c1.w, h);
        h = fmaf(emb[8],  c2.x, h);
        h = fmaf(emb[9],  c2.y, h);
        h = fmaf(emb[10], c2.z, h);
        h = fmaf(emb[11], c2.w, h);
        h = fmaf(emb[12], c3.x, h);
        h = fmaf(emb[13], c3.y, h);
        h = fmaf(emb[14], c3.z, h);
        h = fmaf(emb[15], c3.w, h);
        h = fmaxf(h, 0.f);
        a0 = fmaf(h, w2s[j * 4 + 0], a0);
        a1 = fmaf(h, w2s[j * 4 + 1], a1);
        a2 = fmaf(h, w2s[j * 4 + 2], a2);
    }

    out[b * 3 + 0] = softplusf(a0);
    out[b * 3 + 1] = softplusf(a1);
    out[b * 3 + 2] = softplusf(a2);
}

extern "C" void kernel_launch(void* const* d_in, const int* in_sizes, int n_in,
                              void* d_out, int out_size, void* d_ws, size_t ws_size,
                              hipStream_t stream) {
    const float* vd = (const float*)d_in[0];
    const float* m0 = (const float*)d_in[1];
    const float* m1 = (const float*)d_in[2];
    const float* w1 = (const float*)d_in[3];
    const float* w2 = (const float*)d_in[4];
    float* out = (float*)d_out;
    int B = in_sizes[0] / 3;
    int grid = (B + BLK - 1) / BLK;

    // ws layout: m1p (HW1*32 B) | m0p (HW0*32 B)
    size_t need = (size_t)(HW0 + HW1) * RK * 2;
    if (ws_size >= need) {
        unsigned* m1p = (unsigned*)d_ws;
        unsigned* m0p = (unsigned*)d_ws + (size_t)HW1 * 8;
        repack_kernel<<<(HW1 + BLK - 1) / BLK, BLK, 0, stream>>>(m1, m1p, HW1);
        repack_kernel<<<(HW0 + BLK - 1) / BLK, BLK, 0, stream>>>(m0, m0p, HW0);
        bg_gather_kernel<<<grid, BLK, 0, stream>>>(vd, m0p, m1p, w1, w2, out, B);
    } else {
        bg_fused_kernel<<<grid, BLK, 0, stream>>>(vd, m0, m1, w1, w2, out, B);
    }
}